// Round 1
// baseline (1629.522 us; speedup 1.0000x reference)
//
#include <hip/hip_runtime.h>

typedef __bf16 bf16_t;
typedef __bf16 bf16x8 __attribute__((ext_vector_type(8)));
typedef float f32x4 __attribute__((ext_vector_type(4)));

__device__ inline bf16x8 zero8() {
  bf16x8 v;
#pragma unroll
  for (int i = 0; i < 8; ++i) v[i] = (__bf16)0.0f;
  return v;
}

// ---------------- fp32 NCHW -> bf16 NHWC (LDS tile transpose) ----------------
__global__ __launch_bounds__(256)
void nchw_to_nhwc(const float* __restrict__ in, bf16_t* __restrict__ out,
                  int C, int HW) {
  __shared__ float tile[64][65];
  const int n = blockIdx.z;
  const int c0 = blockIdx.y * 64, p0 = blockIdx.x * 64;
  const int t = threadIdx.x;
  const float* src = in + ((size_t)n * C + c0) * HW + p0;
  const int cl = t >> 6;   // 0..3
  const int pl = t & 63;
#pragma unroll
  for (int i = 0; i < 16; ++i)
    tile[cl + i * 4][pl] = src[(size_t)(cl + i * 4) * HW + pl];
  __syncthreads();
  bf16_t* dst = out + ((size_t)n * HW + p0) * C + c0;
  const int pc = t >> 6;
  const int cc = t & 63;
#pragma unroll
  for (int i = 0; i < 16; ++i)
    dst[(size_t)(pc + i * 4) * C + cc] = (bf16_t)tile[cc][pc + i * 4];
}

// ---------------- elementwise fp32 -> bf16 (lateral 1x1 weights, [O][I]) ----
__global__ __launch_bounds__(256)
void cast_w(const float* __restrict__ in, bf16_t* __restrict__ out, int n) {
  int i = blockIdx.x * 256 + threadIdx.x;
  if (i < n) out[i] = (bf16_t)in[i];
}

// ---------------- OIHW(3x3) fp32 -> [kid][O][I] bf16 ------------------------
__global__ __launch_bounds__(256)
void w3x3_transform(const float* __restrict__ in, bf16_t* __restrict__ out,
                    int O, int I) {
  int idx = blockIdx.x * 256 + threadIdx.x;
  int tot = 9 * O * I;
  if (idx >= tot) return;
  int kid = idx / (O * I);
  int rem = idx - kid * (O * I);
  int o = rem / I;
  int ci = rem - o * I;
  out[idx] = (bf16_t)in[((size_t)o * I + ci) * 9 + kid];
}

// ---------------- dst(NHWC) += up2(src(NHWC)), C == 256 ---------------------
__global__ __launch_bounds__(256)
void up2_add(bf16_t* __restrict__ dst, const bf16_t* __restrict__ src,
             int lw_d, int lhw_d, int tot8) {
  int idx = blockIdx.x * 256 + threadIdx.x;
  if (idx >= tot8) return;
  const int c8 = idx & 31;        // C/8 = 32
  const int pos = idx >> 5;
  const int n = pos >> lhw_d;
  const int rem = pos & ((1 << lhw_d) - 1);
  const int y = rem >> lw_d, x = rem & ((1 << lw_d) - 1);
  const int Ws = 1 << (lw_d - 1);
  const int HWs = 1 << (lhw_d - 2);
  const size_t di = (size_t)idx * 8;
  const size_t si = (((size_t)n * HWs + (y >> 1) * Ws + (x >> 1)) * 32 + c8) * 8;
  bf16x8 d = *(bf16x8*)(dst + di);
  bf16x8 s = *(const bf16x8*)(src + si);
#pragma unroll
  for (int k = 0; k < 8; ++k) d[k] = (bf16_t)((float)d[k] + (float)s[k]);
  *(bf16x8*)(dst + di) = d;
}

// ---------------- implicit-GEMM conv (1x1 / 3x3 pad1), bf16 MFMA ------------
// A: NHWC [M][Cin] bf16 ; Wt: [nk][Cout][Cin] bf16 ; bias fp32
// out: bf16 NHWC [M][Cout] (outb) OR fp32 strided into detector output (outf)
__global__ __launch_bounds__(256, 2)
void conv_mfma(const bf16_t* __restrict__ A, const bf16_t* __restrict__ Wt,
               const float* __restrict__ bias,
               bf16_t* __restrict__ outb, float* __restrict__ outf,
               int H, int W, int lw, int lhw, int Cin, int Cout,
               int nk, int relu, int pos_off, int ch_off) {
  const int HW = 1 << lhw;
  __shared__ bf16_t As[128 * 40];
  __shared__ bf16_t Bs[128 * 40];
  const int t = threadIdx.x;
  const int lane = t & 63, wave = t >> 6;
  const int wm = (wave & 1) * 64, wn = (wave >> 1) * 64;
  const int m0 = blockIdx.x * 128, n0 = blockIdx.y * 128;
  const int seg8 = (t & 3) * 8;     // ci sub-offset within 32-chunk
  const int r0 = t >> 2;            // 0..63 staging row
  const int mA0 = m0 + r0, mA1 = mA0 + 64;
  const int y0 = (mA0 & (HW - 1)) >> lw, x0 = mA0 & (W - 1);
  const int y1 = (mA1 & (HW - 1)) >> lw, x1 = mA1 & (W - 1);
  const bf16_t* Arow0 = A + (size_t)mA0 * Cin + seg8;
  const bf16_t* Arow1 = A + (size_t)mA1 * Cin + seg8;
  const int co0 = n0 + r0, co1 = co0 + 64;
  const bool bv0 = co0 < Cout, bv1 = co1 < Cout;
  const size_t kidStride = (size_t)Cout * Cin;
  const bf16_t* Brow0 = Wt + (size_t)co0 * Cin + seg8;
  const bf16_t* Brow1 = Wt + (size_t)co1 * Cin + seg8;
  const int fr = lane & 15, qd = lane >> 4;

  f32x4 acc[4][4];
#pragma unroll
  for (int i = 0; i < 4; ++i)
#pragma unroll
    for (int j = 0; j < 4; ++j)
#pragma unroll
      for (int r = 0; r < 4; ++r) acc[i][j][r] = 0.0f;

  const int cinb = Cin >> 5;
  int cb = 0, kid = 0;
  int dy = (nk == 1) ? 0 : -1, dx = (nk == 1) ? 0 : -1;
  const int kiters = nk * cinb;
  for (int kk = 0; kk < kiters; ++kk) {
    bf16x8 a0v = zero8(), a1v = zero8(), b0v = zero8(), b1v = zero8();
    const int cboff = cb * 32;
    if (nk == 1) {
      a0v = *(const bf16x8*)(Arow0 + cboff);
      a1v = *(const bf16x8*)(Arow1 + cboff);
    } else {
      const int doff = (dy * W + dx) * Cin + cboff;
      if ((unsigned)(y0 + dy) < (unsigned)H && (unsigned)(x0 + dx) < (unsigned)W)
        a0v = *(const bf16x8*)(Arow0 + doff);
      if ((unsigned)(y1 + dy) < (unsigned)H && (unsigned)(x1 + dx) < (unsigned)W)
        a1v = *(const bf16x8*)(Arow1 + doff);
    }
    const size_t boff = (size_t)kid * kidStride + cboff;
    if (bv0) b0v = *(const bf16x8*)(Brow0 + boff);
    if (bv1) b1v = *(const bf16x8*)(Brow1 + boff);
    __syncthreads();
    *(bf16x8*)&As[r0 * 40 + seg8] = a0v;
    *(bf16x8*)&As[(r0 + 64) * 40 + seg8] = a1v;
    *(bf16x8*)&Bs[r0 * 40 + seg8] = b0v;
    *(bf16x8*)&Bs[(r0 + 64) * 40 + seg8] = b1v;
    __syncthreads();
    bf16x8 af[4], bfv[4];
#pragma unroll
    for (int i = 0; i < 4; ++i)
      af[i] = *(const bf16x8*)&As[(wm + i * 16 + fr) * 40 + qd * 8];
#pragma unroll
    for (int j = 0; j < 4; ++j)
      bfv[j] = *(const bf16x8*)&Bs[(wn + j * 16 + fr) * 40 + qd * 8];
#pragma unroll
    for (int i = 0; i < 4; ++i)
#pragma unroll
      for (int j = 0; j < 4; ++j)
        acc[i][j] = __builtin_amdgcn_mfma_f32_16x16x32_bf16(af[i], bfv[j],
                                                            acc[i][j], 0, 0, 0);
    if (++cb == cinb) {
      cb = 0; ++kid;
      if (++dx == 2) { dx = -1; ++dy; }
    }
  }

  // epilogue: D layout col=lane&15, row=(lane>>4)*4+reg  [m89/m91]
#pragma unroll
  for (int i = 0; i < 4; ++i) {
    const int mrow = m0 + wm + i * 16 + qd * 4;
#pragma unroll
    for (int j = 0; j < 4; ++j) {
      const int co = n0 + wn + j * 16 + fr;
      if (co < Cout) {
        const float bv = bias[co];
#pragma unroll
        for (int r = 0; r < 4; ++r) {
          float v = acc[i][j][r] + bv;
          if (relu) v = fmaxf(v, 0.0f);
          const int m = mrow + r;
          if (outf) {
            const int n = m >> lhw, hw = m & (HW - 1);
            outf[((size_t)n * 5376 + pos_off + hw) * 252 + ch_off + co] = v;
          } else {
            outb[(size_t)m * Cout + co] = (bf16_t)v;
          }
        }
      }
    }
  }
}

// ---------------- anchors ----------------------------------------------------
__global__ __launch_bounds__(256)
void anchors_k(float* __restrict__ out) {
  int r = blockIdx.x * 256 + threadIdx.x;
  if (r >= 16128) return;
  int local, w, stride;
  float bs;
  if (r < 12288)      { local = r;          w = 64; stride = 8;  bs = 32.f;  }
  else if (r < 15360) { local = r - 12288;  w = 32; stride = 16; bs = 64.f;  }
  else                { local = r - 15360;  w = 16; stride = 32; bs = 128.f; }
  const int a = local % 3;
  const int s = local / 3;
  const int y = s / w, x = s - y * w;
  const float ar = (a == 0) ? 0.5f : (a == 1) ? 1.0f : 2.0f;
  const float sq = sqrtf(ar);
  const float hw_ = bs * sq * 0.5f, hh = bs / sq * 0.5f;
  const float cx = (float)x * (float)stride, cy = (float)y * (float)stride;
  out[(size_t)r * 4 + 0] = cx - hw_;
  out[(size_t)r * 4 + 1] = cy - hh;
  out[(size_t)r * 4 + 2] = cx + hw_;
  out[(size_t)r * 4 + 3] = cy + hh;
}

// ---------------- launch -----------------------------------------------------
extern "C" void kernel_launch(void* const* d_in, const int* in_sizes, int n_in,
                              void* d_out, int out_size, void* d_ws, size_t ws_size,
                              hipStream_t stream) {
  const float* feat3 = (const float*)d_in[0];
  const float* feat4 = (const float*)d_in[1];
  const float* feat5 = (const float*)d_in[2];
  const float* lw0 = (const float*)d_in[3];  const float* lb0 = (const float*)d_in[4];
  const float* lw1 = (const float*)d_in[5];  const float* lb1 = (const float*)d_in[6];
  const float* lw2 = (const float*)d_in[7];  const float* lb2 = (const float*)d_in[8];
  const float* fw0 = (const float*)d_in[9];  const float* fb0 = (const float*)d_in[10];
  const float* fw1 = (const float*)d_in[11]; const float* fb1 = (const float*)d_in[12];
  const float* fw2 = (const float*)d_in[13]; const float* fb2 = (const float*)d_in[14];
  const float* cw0 = (const float*)d_in[15]; const float* cb0 = (const float*)d_in[16];
  const float* cw1 = (const float*)d_in[17]; const float* cb1 = (const float*)d_in[18];
  const float* cw2 = (const float*)d_in[19]; const float* cb2 = (const float*)d_in[20];
  const float* rw0 = (const float*)d_in[21]; const float* rb0 = (const float*)d_in[22];
  const float* rw1 = (const float*)d_in[23]; const float* rb1 = (const float*)d_in[24];
  const float* rw2 = (const float*)d_in[25]; const float* rb2 = (const float*)d_in[26];

  char* ws = (char*)d_ws;
  float* out = (float*)d_out;

  // ---- workspace layout (bytes) ----
  bf16_t* XS3 = (bf16_t*)(ws + 0);          // 8*4096*512  bf16 = 33554432 B
  bf16_t* XS4 = (bf16_t*)(ws + 33554432);   // 8*1024*1024 = 16777216 B
  bf16_t* XS5 = (bf16_t*)(ws + 50331648);   // 8*256*2048  = 8388608 B
  bf16_t* L0  = (bf16_t*)(ws + 58720256);   // 8*4096*256  = 16777216 B
  bf16_t* L1  = (bf16_t*)(ws + 75497472);   // 4194304 B
  bf16_t* L2  = (bf16_t*)(ws + 79691776);   // 1048576 B
  bf16_t* LWT0 = (bf16_t*)(ws + 80740352);  // 256*512
  bf16_t* LWT1 = (bf16_t*)(ws + 81002496);  // 256*1024
  bf16_t* LWT2 = (bf16_t*)(ws + 81526784);  // 256*2048
  bf16_t* FWT0 = (bf16_t*)(ws + 82575360);  // 9*256*256 each
  bf16_t* FWT1 = (bf16_t*)(ws + 83755008);
  bf16_t* FWT2 = (bf16_t*)(ws + 84934656);
  bf16_t* CWT0 = (bf16_t*)(ws + 86114304);
  bf16_t* CWT1 = (bf16_t*)(ws + 87293952);
  bf16_t* CWT2 = (bf16_t*)(ws + 88473600);  // 9*240*256
  bf16_t* RWT0 = (bf16_t*)(ws + 89579520);
  bf16_t* RWT1 = (bf16_t*)(ws + 90759168);
  bf16_t* RWT2 = (bf16_t*)(ws + 91938816);  // 9*12*256
  // aliases (dead regions reused)
  bf16_t* TA = (bf16_t*)(ws + 0);           // over XS3 (16777216 B)
  bf16_t* TB = (bf16_t*)(ws + 16777216);    // over XS3 (16777216 B)
  bf16_t* P0 = (bf16_t*)(ws + 33554432);    // over XS4 (16777216 B)
  bf16_t* P1 = (bf16_t*)(ws + 50331648);    // over XS5 (4194304 B)
  bf16_t* P2 = (bf16_t*)(ws + 54525952);    // over XS5 (1048576 B)

  // 1. activation casts to NHWC bf16
  nchw_to_nhwc<<<dim3(64, 8, 8),  256, 0, stream>>>(feat3, XS3, 512, 4096);
  nchw_to_nhwc<<<dim3(16, 16, 8), 256, 0, stream>>>(feat4, XS4, 1024, 1024);
  nchw_to_nhwc<<<dim3(4, 32, 8),  256, 0, stream>>>(feat5, XS5, 2048, 256);

  // 2. weight transforms
  cast_w<<<dim3(512),  256, 0, stream>>>(lw0, LWT0, 131072);
  cast_w<<<dim3(1024), 256, 0, stream>>>(lw1, LWT1, 262144);
  cast_w<<<dim3(2048), 256, 0, stream>>>(lw2, LWT2, 524288);
  w3x3_transform<<<dim3(2304), 256, 0, stream>>>(fw0, FWT0, 256, 256);
  w3x3_transform<<<dim3(2304), 256, 0, stream>>>(fw1, FWT1, 256, 256);
  w3x3_transform<<<dim3(2304), 256, 0, stream>>>(fw2, FWT2, 256, 256);
  w3x3_transform<<<dim3(2304), 256, 0, stream>>>(cw0, CWT0, 256, 256);
  w3x3_transform<<<dim3(2304), 256, 0, stream>>>(cw1, CWT1, 256, 256);
  w3x3_transform<<<dim3(2160), 256, 0, stream>>>(cw2, CWT2, 240, 256);
  w3x3_transform<<<dim3(2304), 256, 0, stream>>>(rw0, RWT0, 256, 256);
  w3x3_transform<<<dim3(2304), 256, 0, stream>>>(rw1, RWT1, 256, 256);
  w3x3_transform<<<dim3(108),  256, 0, stream>>>(rw2, RWT2, 12, 256);

  // 3. lateral 1x1 convs  (H, W, lw, lhw, Cin, Cout, nk, relu, pos, ch)
  conv_mfma<<<dim3(256, 2), 256, 0, stream>>>(XS3, LWT0, lb0, L0, nullptr,
      64, 64, 6, 12, 512, 256, 1, 0, 0, 0);
  conv_mfma<<<dim3(64, 2), 256, 0, stream>>>(XS4, LWT1, lb1, L1, nullptr,
      32, 32, 5, 10, 1024, 256, 1, 0, 0, 0);
  conv_mfma<<<dim3(16, 2), 256, 0, stream>>>(XS5, LWT2, lb2, L2, nullptr,
      16, 16, 4, 8, 2048, 256, 1, 0, 0, 0);

  // 4. top-down fusion
  up2_add<<<dim3(1024), 256, 0, stream>>>(L1, L2, 5, 10, 262144);
  up2_add<<<dim3(4096), 256, 0, stream>>>(L0, L1, 6, 12, 1048576);

  // 5. FPN 3x3 output convs
  conv_mfma<<<dim3(256, 2), 256, 0, stream>>>(L0, FWT0, fb0, P0, nullptr,
      64, 64, 6, 12, 256, 256, 9, 0, 0, 0);
  conv_mfma<<<dim3(64, 2), 256, 0, stream>>>(L1, FWT1, fb1, P1, nullptr,
      32, 32, 5, 10, 256, 256, 9, 0, 0, 0);
  conv_mfma<<<dim3(16, 2), 256, 0, stream>>>(L2, FWT2, fb2, P2, nullptr,
      16, 16, 4, 8, 256, 256, 9, 0, 0, 0);

  // 6. towers per level
  struct Lv { bf16_t* p; int H, W, lw, lhw, mt, pos; };
  Lv lv[3] = { {P0, 64, 64, 6, 12, 256, 0},
               {P1, 32, 32, 5, 10, 64, 4096},
               {P2, 16, 16, 4, 8, 16, 5120} };
  for (int l = 0; l < 3; ++l) {
    Lv& v = lv[l];
    // cls tower
    conv_mfma<<<dim3(v.mt, 2), 256, 0, stream>>>(v.p, CWT0, cb0, TA, nullptr,
        v.H, v.W, v.lw, v.lhw, 256, 256, 9, 1, 0, 0);
    conv_mfma<<<dim3(v.mt, 2), 256, 0, stream>>>(TA, CWT1, cb1, TB, nullptr,
        v.H, v.W, v.lw, v.lhw, 256, 256, 9, 1, 0, 0);
    conv_mfma<<<dim3(v.mt, 2), 256, 0, stream>>>(TB, CWT2, cb2, nullptr, out,
        v.H, v.W, v.lw, v.lhw, 256, 240, 9, 0, v.pos, 0);
    // reg tower
    conv_mfma<<<dim3(v.mt, 2), 256, 0, stream>>>(v.p, RWT0, rb0, TA, nullptr,
        v.H, v.W, v.lw, v.lhw, 256, 256, 9, 1, 0, 0);
    conv_mfma<<<dim3(v.mt, 2), 256, 0, stream>>>(TA, RWT1, rb1, TB, nullptr,
        v.H, v.W, v.lw, v.lhw, 256, 256, 9, 1, 0, 0);
    conv_mfma<<<dim3(v.mt, 1), 256, 0, stream>>>(TB, RWT2, rb2, nullptr, out,
        v.H, v.W, v.lw, v.lhw, 256, 12, 9, 0, v.pos, 240);
  }

  // 7. anchors
  anchors_k<<<dim3(63), 256, 0, stream>>>(out + 10838016);
}

// Round 2
// 771.995 us; speedup vs baseline: 2.1108x; 2.1108x over previous
//
#include <hip/hip_runtime.h>

typedef __bf16 bf16_t;
typedef __bf16 bf16x8 __attribute__((ext_vector_type(8)));
typedef float f32x4 __attribute__((ext_vector_type(4)));

// async global->LDS, 16B per lane, wave-uniform LDS base + lane*16
__device__ inline void gl_lds16(const bf16_t* g, bf16_t* l) {
  __builtin_amdgcn_global_load_lds(
      (const __attribute__((address_space(1))) void*)g,
      (__attribute__((address_space(3))) void*)l, 16, 0, 0);
}

// ---------------- fp32 NCHW -> bf16 NHWC (LDS tile transpose) ----------------
__global__ __launch_bounds__(256)
void nchw_to_nhwc(const float* __restrict__ in, bf16_t* __restrict__ out,
                  int C, int HW) {
  __shared__ float tile[64][65];
  const int n = blockIdx.z;
  const int c0 = blockIdx.y * 64, p0 = blockIdx.x * 64;
  const int t = threadIdx.x;
  const float* src = in + ((size_t)n * C + c0) * HW + p0;
  const int cl = t >> 6;
  const int pl = t & 63;
#pragma unroll
  for (int i = 0; i < 16; ++i)
    tile[cl + i * 4][pl] = src[(size_t)(cl + i * 4) * HW + pl];
  __syncthreads();
  bf16_t* dst = out + ((size_t)n * HW + p0) * C + c0;
  const int pc = t >> 6;
  const int cc = t & 63;
#pragma unroll
  for (int i = 0; i < 16; ++i)
    dst[(size_t)(pc + i * 4) * C + cc] = (bf16_t)tile[cc][pc + i * 4];
}

// ---------------- all weight transforms in one kernel ------------------------
struct WSrc {
  const float *lw0, *lw1, *lw2;
  const float* w9[9];   // fw0,fw1,fw2,cw0,cw1,cw2,rw0,rw1,rw2
  int O9[9];            // 256,256,256,256,256,240,256,256,12
};
__global__ __launch_bounds__(256)
void weight_prep(WSrc s, bf16_t* __restrict__ LWT0, bf16_t* __restrict__ LWT1,
                 bf16_t* __restrict__ LWT2, bf16_t* __restrict__ W33) {
  int idx = blockIdx.x * 256 + threadIdx.x;
  if (idx < 131072) { LWT0[idx] = (bf16_t)s.lw0[idx]; return; }
  if (idx < 393216) { int i = idx - 131072; LWT1[i] = (bf16_t)s.lw1[i]; return; }
  if (idx < 917504) { int i = idx - 393216; LWT2[i] = (bf16_t)s.lw2[i]; return; }
  int t2 = idx - 917504;
  if (t2 >= 9 * 589824) return;
  int sgi = t2 / 589824;
  int r = t2 - sgi * 589824;
  int kid = r >> 16;            // 9 taps * 65536
  int rem = r & 65535;
  int o = rem >> 8, ci = rem & 255;
  const float* src = s.w9[sgi];
  int O = s.O9[sgi];
  W33[t2] = (o < O) ? (bf16_t)src[((size_t)o * 256 + ci) * 9 + kid] : (bf16_t)0.0f;
}

// ---------------- dst(padded NHWC) += up2(src(padded NHWC)), C == 256 --------
__global__ __launch_bounds__(256)
void up2_add_p(bf16_t* __restrict__ dst, const bf16_t* __restrict__ src,
               int lw, int lhw, int dWp, int dNs, int sWp, int sNs, int tot8) {
  int idx = blockIdx.x * 256 + threadIdx.x;
  if (idx >= tot8) return;
  const int c8 = idx & 31;
  const int pos = idx >> 5;
  const int n = pos >> lhw;
  const int rem = pos & ((1 << lhw) - 1);
  const int y = rem >> lw, x = rem & ((1 << lw) - 1);
  bf16_t* d = dst + ((size_t)n * dNs + (y + 1) * dWp + (x + 1)) * 256 + c8 * 8;
  const bf16_t* sp = src + ((size_t)n * sNs + ((y >> 1) + 1) * sWp + ((x >> 1) + 1)) * 256 + c8 * 8;
  bf16x8 dv = *(bf16x8*)d;
  bf16x8 sv = *(const bf16x8*)sp;
#pragma unroll
  for (int k = 0; k < 8; ++k) dv[k] = (bf16_t)((float)dv[k] + (float)sv[k]);
  *(bf16x8*)d = dv;
}

// ---------------- batched implicit-GEMM conv, bf16 MFMA, global_load_lds -----
struct Job {
  const bf16_t* A;    // NHWC, padded pitch for 3x3 (halo zeros), unpadded for 1x1
  const bf16_t* Wt;   // [nk][256][Cin] bf16 (rows >= Cout zero-filled)
  const float* bias;
  bf16_t* outb;       // padded NHWC out (C=256), or null if use_outf
  int mtiles, ntiles; // 128-row M tiles, 128-col N tiles
  int lw, lhw;        // interior log2(W), log2(H*W)
  int Wp, nsA;        // input row pitch, per-batch pixel stride
  int oWp, onstride;  // output row pitch, per-batch pixel stride
  int Cin, nk, relu, Cout, pos_off, ch_off, use_outf, pad_;
};
struct JobPack { Job j[6]; };

__global__ __launch_bounds__(256, 2)
void conv_batch(JobPack jp, float* __restrict__ outf) {
  __shared__ __align__(16) bf16_t As[128 * 32];
  __shared__ __align__(16) bf16_t Bs[128 * 32];
  int b = blockIdx.x, ji = 0;
#pragma unroll 1
  for (; ji < 5; ++ji) {
    int sz = jp.j[ji].mtiles * jp.j[ji].ntiles;
    if (b < sz) break;
    b -= sz;
  }
  const Job J = jp.j[ji];
  const int nt = (J.ntiles == 2) ? (b & 1) : 0;
  const int mt = (J.ntiles == 2) ? (b >> 1) : b;
  const int m0 = mt * 128, n0 = nt * 128;
  const int t = threadIdx.x, l = t & 63, w = t >> 6;
  const int W = 1 << J.lw, HW = 1 << J.lhw;

  // staging assignment: wave w covers rows [w*32, w*32+32) via q in {0,1}
  const int sr = l >> 2, seg = (l & 3) * 8;
  const bf16_t* aptr[2];
  const bf16_t* bptr[2];
  bf16_t* alds[2];
  bf16_t* blds[2];
#pragma unroll
  for (int q = 0; q < 2; ++q) {
    const int r = w * 32 + q * 16 + sr;
    const int mA = m0 + r;
    const int n = mA >> J.lhw;
    const int hw = mA & (HW - 1);
    const int y = hw >> J.lw, x = hw & (W - 1);
    aptr[q] = J.A + ((size_t)n * J.nsA + y * J.Wp + x) * J.Cin + seg;
    alds[q] = &As[(w * 32 + q * 16) * 32];
    const int co = n0 + w * 32 + q * 16 + sr;
    bptr[q] = J.Wt + (size_t)co * J.Cin + seg;
    blds[q] = &Bs[(w * 32 + q * 16) * 32];
  }

  const int fr = l & 15, qd = l >> 4;
  const int wm = (w & 1) * 64, wn = (w >> 1) * 64;

  f32x4 acc[4][4];
#pragma unroll
  for (int i = 0; i < 4; ++i)
#pragma unroll
    for (int j = 0; j < 4; ++j)
#pragma unroll
      for (int r = 0; r < 4; ++r) acc[i][j][r] = 0.0f;

  const int cinb = J.Cin >> 5;
  const int kiters = J.nk * cinb;
  const int colA = J.Cin - (cinb - 1) * 32;            // dx step
  const int rowA = (J.Wp - 2) * J.Cin - (cinb - 1) * 32; // dy step (dx wrap)
  const int wrapB = 256 * J.Cin - (cinb - 1) * 32;
  int cb = 0, kid = 0;

#pragma unroll 1
  for (int kk = 0; kk < kiters; ++kk) {
    __syncthreads();
    gl_lds16(aptr[0], alds[0]);
    gl_lds16(aptr[1], alds[1]);
    gl_lds16(bptr[0], blds[0]);
    gl_lds16(bptr[1], blds[1]);
    __syncthreads();
    // uniform pointer advance
    int dA = 32, dB = 32;
    if (++cb == cinb) {
      cb = 0; ++kid;
      dB = wrapB;
      dA = ((kid == 3) | (kid == 6)) ? rowA : colA;
    }
    aptr[0] += dA; aptr[1] += dA; bptr[0] += dB; bptr[1] += dB;

    bf16x8 af[4], bfv[4];
#pragma unroll
    for (int i = 0; i < 4; ++i)
      af[i] = *(const bf16x8*)&As[(wm + i * 16 + fr) * 32 + qd * 8];
#pragma unroll
    for (int j = 0; j < 4; ++j)
      bfv[j] = *(const bf16x8*)&Bs[(wn + j * 16 + fr) * 32 + qd * 8];
#pragma unroll
    for (int i = 0; i < 4; ++i)
#pragma unroll
      for (int j = 0; j < 4; ++j)
        acc[i][j] = __builtin_amdgcn_mfma_f32_16x16x32_bf16(af[i], bfv[j],
                                                            acc[i][j], 0, 0, 0);
  }

  // epilogue: D layout col=lane&15, row=(lane>>4)*4+reg
#pragma unroll
  for (int i = 0; i < 4; ++i) {
    const int mrow = m0 + wm + i * 16 + qd * 4;
#pragma unroll
    for (int j = 0; j < 4; ++j) {
      const int co = n0 + wn + j * 16 + fr;
      if (co < J.Cout) {
        const float bv = J.bias[co];
#pragma unroll
        for (int r = 0; r < 4; ++r) {
          float v = acc[i][j][r] + bv;
          if (J.relu) v = fmaxf(v, 0.0f);
          const int m = mrow + r;
          const int n = m >> J.lhw, hw = m & (HW - 1);
          if (J.use_outf) {
            outf[((size_t)n * 5376 + J.pos_off + hw) * 252 + J.ch_off + co] = v;
          } else {
            const int y = hw >> J.lw, x = hw & (W - 1);
            J.outb[((size_t)n * J.onstride + (y + 1) * J.oWp + (x + 1)) * 256 + co] =
                (bf16_t)v;
          }
        }
      }
    }
  }
}

// ---------------- anchors ----------------------------------------------------
__global__ __launch_bounds__(256)
void anchors_k(float* __restrict__ out) {
  int r = blockIdx.x * 256 + threadIdx.x;
  if (r >= 16128) return;
  int local, w, stride;
  float bs;
  if (r < 12288)      { local = r;          w = 64; stride = 8;  bs = 32.f;  }
  else if (r < 15360) { local = r - 12288;  w = 32; stride = 16; bs = 64.f;  }
  else                { local = r - 15360;  w = 16; stride = 32; bs = 128.f; }
  const int a = local % 3;
  const int s = local / 3;
  const int y = s / w, x = s - y * w;
  const float ar = (a == 0) ? 0.5f : (a == 1) ? 1.0f : 2.0f;
  const float sq = sqrtf(ar);
  const float hw_ = bs * sq * 0.5f, hh = bs / sq * 0.5f;
  const float cx = (float)x * (float)stride, cy = (float)y * (float)stride;
  out[(size_t)r * 4 + 0] = cx - hw_;
  out[(size_t)r * 4 + 1] = cy - hh;
  out[(size_t)r * 4 + 2] = cx + hw_;
  out[(size_t)r * 4 + 3] = cy + hh;
}

// ---------------- launch -----------------------------------------------------
extern "C" void kernel_launch(void* const* d_in, const int* in_sizes, int n_in,
                              void* d_out, int out_size, void* d_ws, size_t ws_size,
                              hipStream_t stream) {
  const float* feat3 = (const float*)d_in[0];
  const float* feat4 = (const float*)d_in[1];
  const float* feat5 = (const float*)d_in[2];
  const float* lw0 = (const float*)d_in[3];  const float* lb0 = (const float*)d_in[4];
  const float* lw1 = (const float*)d_in[5];  const float* lb1 = (const float*)d_in[6];
  const float* lw2 = (const float*)d_in[7];  const float* lb2 = (const float*)d_in[8];
  const float* fw0 = (const float*)d_in[9];  const float* fb0 = (const float*)d_in[10];
  const float* fw1 = (const float*)d_in[11]; const float* fb1 = (const float*)d_in[12];
  const float* fw2 = (const float*)d_in[13]; const float* fb2 = (const float*)d_in[14];
  const float* cw0 = (const float*)d_in[15]; const float* cb0 = (const float*)d_in[16];
  const float* cw1 = (const float*)d_in[17]; const float* cb1 = (const float*)d_in[18];
  const float* cw2 = (const float*)d_in[19]; const float* cb2 = (const float*)d_in[20];
  const float* rw0 = (const float*)d_in[21]; const float* rb0 = (const float*)d_in[22];
  const float* rw1 = (const float*)d_in[23]; const float* rb1 = (const float*)d_in[24];
  const float* rw2 = (const float*)d_in[25]; const float* rb2 = (const float*)d_in[26];

  char* ws = (char*)d_ws;
  float* out = (float*)d_out;

  // ---- workspace layout (bytes) ----
  bf16_t* XS3 = (bf16_t*)(ws + 0);            // 33,554,432
  bf16_t* XS4 = (bf16_t*)(ws + 33554432);     // 16,777,216
  bf16_t* XS5 = (bf16_t*)(ws + 50331648);     //  8,388,608
  bf16_t* Lp0 = (bf16_t*)(ws + 58720256);     // 8*66*66*256*2 = 17,842,176
  bf16_t* Lp1 = (bf16_t*)(ws + 76562432);     // 8*34*34*256*2 =  4,734,976
  bf16_t* Lp2 = (bf16_t*)(ws + 81297408);     // 8*18*18*256*2 =  1,327,104
  bf16_t* Pp0 = (bf16_t*)(ws + 82624512);     // 17,842,176
  bf16_t* Pp1 = (bf16_t*)(ws + 100466688);    //  4,734,976
  bf16_t* Pp2 = (bf16_t*)(ws + 105201664);    //  1,327,104
  bf16_t* LWT0 = (bf16_t*)(ws + 106528768);   //    262,144
  bf16_t* LWT1 = (bf16_t*)(ws + 106790912);   //    524,288
  bf16_t* LWT2 = (bf16_t*)(ws + 107315200);   //  1,048,576
  bf16_t* W33  = (bf16_t*)(ws + 108363776);   // 9 * 1,179,648 = 10,616,832 (end 118,980,608)
  bf16_t* FWT0 = W33 + 0 * 589824;
  bf16_t* FWT1 = W33 + 1 * 589824;
  bf16_t* FWT2 = W33 + 2 * 589824;
  bf16_t* CWT0 = W33 + 3 * 589824;
  bf16_t* CWT1 = W33 + 4 * 589824;
  bf16_t* CWT2 = W33 + 5 * 589824;
  bf16_t* RWT0 = W33 + 6 * 589824;
  bf16_t* RWT1 = W33 + 7 * 589824;
  bf16_t* RWT2 = W33 + 8 * 589824;
  // T region: aliases XS3+XS4 (dead after laterals)
  bf16_t* TAc0 = (bf16_t*)(ws + 0);
  bf16_t* TAr0 = (bf16_t*)(ws + 17842176);
  bf16_t* TAc1 = (bf16_t*)(ws + 35684352);
  bf16_t* TAr1 = (bf16_t*)(ws + 40419328);
  bf16_t* TAc2 = (bf16_t*)(ws + 45154304);
  bf16_t* TAr2 = (bf16_t*)(ws + 46481408);    // end 47,808,512
  bf16_t* TBc0 = Pp0; bf16_t* TBr0 = Lp0;
  bf16_t* TBc1 = Pp1; bf16_t* TBr1 = Lp1;
  bf16_t* TBc2 = Pp2; bf16_t* TBr2 = Lp2;

  // 1. weight prep (single launch)
  WSrc wsrc;
  wsrc.lw0 = lw0; wsrc.lw1 = lw1; wsrc.lw2 = lw2;
  const float* w9s[9] = {fw0, fw1, fw2, cw0, cw1, cw2, rw0, rw1, rw2};
  int o9s[9] = {256, 256, 256, 256, 256, 240, 256, 256, 12};
  for (int i = 0; i < 9; ++i) { wsrc.w9[i] = w9s[i]; wsrc.O9[i] = o9s[i]; }
  weight_prep<<<dim3(24320), 256, 0, stream>>>(wsrc, LWT0, LWT1, LWT2, W33);

  // 2. activation casts to NHWC bf16 (unpadded; laterals are 1x1)
  nchw_to_nhwc<<<dim3(64, 8, 8),  256, 0, stream>>>(feat3, XS3, 512, 4096);
  nchw_to_nhwc<<<dim3(16, 16, 8), 256, 0, stream>>>(feat4, XS4, 1024, 1024);
  nchw_to_nhwc<<<dim3(4, 32, 8),  256, 0, stream>>>(feat5, XS5, 2048, 256);

  // 3. zero padded Lp/Pp region (halo zeros; interiors overwritten by convs)
  hipMemsetAsync(ws + 58720256, 0, 47808512, stream);

  auto mkjob = [](const bf16_t* A, const bf16_t* Wt, const float* bias,
                  bf16_t* outb, int mtiles, int ntiles, int lw, int lhw,
                  int Wp, int nsA, int oWp, int onstride, int Cin, int nk,
                  int relu, int Cout, int pos_off, int ch_off, int use_outf) {
    Job j;
    j.A = A; j.Wt = Wt; j.bias = bias; j.outb = outb;
    j.mtiles = mtiles; j.ntiles = ntiles; j.lw = lw; j.lhw = lhw;
    j.Wp = Wp; j.nsA = nsA; j.oWp = oWp; j.onstride = onstride;
    j.Cin = Cin; j.nk = nk; j.relu = relu; j.Cout = Cout;
    j.pos_off = pos_off; j.ch_off = ch_off; j.use_outf = use_outf; j.pad_ = 0;
    return j;
  };

  // 4. lateral 1x1 convs (fused, 672 blocks)
  {
    JobPack jp;
    jp.j[0] = mkjob(XS3, LWT0, lb0, Lp0, 256, 2, 6, 12, 64, 4096, 66, 4356, 512, 1, 0, 256, 0, 0, 0);
    jp.j[1] = mkjob(XS4, LWT1, lb1, Lp1, 64, 2, 5, 10, 32, 1024, 34, 1156, 1024, 1, 0, 256, 0, 0, 0);
    jp.j[2] = mkjob(XS5, LWT2, lb2, Lp2, 16, 2, 4, 8, 16, 256, 18, 324, 2048, 1, 0, 256, 0, 0, 0);
    jp.j[3] = jp.j[4] = jp.j[5] = jp.j[2]; jp.j[3].mtiles = jp.j[4].mtiles = jp.j[5].mtiles = 0;
    conv_batch<<<dim3(672), 256, 0, stream>>>(jp, out);
  }

  // 5. zero T region (XS3/XS4 now dead)
  hipMemsetAsync(ws + 0, 0, 47808512, stream);

  // 6. top-down fusion (padded in/out)
  up2_add_p<<<dim3(1024), 256, 0, stream>>>(Lp1, Lp2, 5, 10, 34, 1156, 18, 324, 262144);
  up2_add_p<<<dim3(4096), 256, 0, stream>>>(Lp0, Lp1, 6, 12, 66, 4356, 34, 1156, 1048576);

  // 7. FPN 3x3 convs (fused, 672 blocks)
  {
    JobPack jp;
    jp.j[0] = mkjob(Lp0, FWT0, fb0, Pp0, 256, 2, 6, 12, 66, 4356, 66, 4356, 256, 9, 0, 256, 0, 0, 0);
    jp.j[1] = mkjob(Lp1, FWT1, fb1, Pp1, 64, 2, 5, 10, 34, 1156, 34, 1156, 256, 9, 0, 256, 0, 0, 0);
    jp.j[2] = mkjob(Lp2, FWT2, fb2, Pp2, 16, 2, 4, 8, 18, 324, 18, 324, 256, 9, 0, 256, 0, 0, 0);
    jp.j[3] = jp.j[4] = jp.j[5] = jp.j[2]; jp.j[3].mtiles = jp.j[4].mtiles = jp.j[5].mtiles = 0;
    conv_batch<<<dim3(672), 256, 0, stream>>>(jp, out);
  }

  // 8. tower stage 1 (cls+reg, all levels; 1344 blocks)
  {
    JobPack jp;
    jp.j[0] = mkjob(Pp0, CWT0, cb0, TAc0, 256, 2, 6, 12, 66, 4356, 66, 4356, 256, 9, 1, 256, 0, 0, 0);
    jp.j[1] = mkjob(Pp0, RWT0, rb0, TAr0, 256, 2, 6, 12, 66, 4356, 66, 4356, 256, 9, 1, 256, 0, 0, 0);
    jp.j[2] = mkjob(Pp1, CWT0, cb0, TAc1, 64, 2, 5, 10, 34, 1156, 34, 1156, 256, 9, 1, 256, 0, 0, 0);
    jp.j[3] = mkjob(Pp1, RWT0, rb0, TAr1, 64, 2, 5, 10, 34, 1156, 34, 1156, 256, 9, 1, 256, 0, 0, 0);
    jp.j[4] = mkjob(Pp2, CWT0, cb0, TAc2, 16, 2, 4, 8, 18, 324, 18, 324, 256, 9, 1, 256, 0, 0, 0);
    jp.j[5] = mkjob(Pp2, RWT0, rb0, TAr2, 16, 2, 4, 8, 18, 324, 18, 324, 256, 9, 1, 256, 0, 0, 0);
    conv_batch<<<dim3(1344), 256, 0, stream>>>(jp, out);
  }

  // 9. tower stage 2 (1344 blocks)
  {
    JobPack jp;
    jp.j[0] = mkjob(TAc0, CWT1, cb1, TBc0, 256, 2, 6, 12, 66, 4356, 66, 4356, 256, 9, 1, 256, 0, 0, 0);
    jp.j[1] = mkjob(TAr0, RWT1, rb1, TBr0, 256, 2, 6, 12, 66, 4356, 66, 4356, 256, 9, 1, 256, 0, 0, 0);
    jp.j[2] = mkjob(TAc1, CWT1, cb1, TBc1, 64, 2, 5, 10, 34, 1156, 34, 1156, 256, 9, 1, 256, 0, 0, 0);
    jp.j[3] = mkjob(TAr1, RWT1, rb1, TBr1, 64, 2, 5, 10, 34, 1156, 34, 1156, 256, 9, 1, 256, 0, 0, 0);
    jp.j[4] = mkjob(TAc2, CWT1, cb1, TBc2, 16, 2, 4, 8, 18, 324, 18, 324, 256, 9, 1, 256, 0, 0, 0);
    jp.j[5] = mkjob(TAr2, RWT1, rb1, TBr2, 16, 2, 4, 8, 18, 324, 18, 324, 256, 9, 1, 256, 0, 0, 0);
    conv_batch<<<dim3(1344), 256, 0, stream>>>(jp, out);
  }

  // 10. tower stage 3 -> detector output (1008 blocks)
  {
    JobPack jp;
    jp.j[0] = mkjob(TBc0, CWT2, cb2, nullptr, 256, 2, 6, 12, 66, 4356, 0, 0, 256, 9, 0, 240, 0, 0, 1);
    jp.j[1] = mkjob(TBr0, RWT2, rb2, nullptr, 256, 1, 6, 12, 66, 4356, 0, 0, 256, 9, 0, 12, 0, 240, 1);
    jp.j[2] = mkjob(TBc1, CWT2, cb2, nullptr, 64, 2, 5, 10, 34, 1156, 0, 0, 256, 9, 0, 240, 4096, 0, 1);
    jp.j[3] = mkjob(TBr1, RWT2, rb2, nullptr, 64, 1, 5, 10, 34, 1156, 0, 0, 256, 9, 0, 12, 4096, 240, 1);
    jp.j[4] = mkjob(TBc2, CWT2, cb2, nullptr, 16, 2, 4, 8, 18, 324, 0, 0, 256, 9, 0, 240, 5120, 0, 1);
    jp.j[5] = mkjob(TBr2, RWT2, rb2, nullptr, 16, 1, 4, 8, 18, 324, 0, 0, 256, 9, 0, 12, 5120, 240, 1);
    conv_batch<<<dim3(1008), 256, 0, stream>>>(jp, out);
  }

  // 11. anchors
  anchors_k<<<dim3(63), 256, 0, stream>>>(out + 10838016);
}

// Round 3
// 664.160 us; speedup vs baseline: 2.4535x; 1.1624x over previous
//
#include <hip/hip_runtime.h>

typedef __bf16 bf16_t;
typedef __bf16 bf16x8 __attribute__((ext_vector_type(8)));
typedef float f32x4 __attribute__((ext_vector_type(4)));

// async global->LDS, 16B per lane, wave-uniform LDS base + lane*16
__device__ inline void gl_lds16(const bf16_t* g, bf16_t* l) {
  __builtin_amdgcn_global_load_lds(
      (const __attribute__((address_space(1))) void*)g,
      (__attribute__((address_space(3))) void*)l, 16, 0, 0);
}

// ---------------- fp32 NCHW -> bf16 NHWC (LDS tile transpose) ----------------
__global__ __launch_bounds__(256)
void nchw_to_nhwc(const float* __restrict__ in, bf16_t* __restrict__ out,
                  int C, int HW) {
  __shared__ float tile[64][65];
  const int n = blockIdx.z;
  const int c0 = blockIdx.y * 64, p0 = blockIdx.x * 64;
  const int t = threadIdx.x;
  const float* src = in + ((size_t)n * C + c0) * HW + p0;
  const int cl = t >> 6;
  const int pl = t & 63;
#pragma unroll
  for (int i = 0; i < 16; ++i)
    tile[cl + i * 4][pl] = src[(size_t)(cl + i * 4) * HW + pl];
  __syncthreads();
  bf16_t* dst = out + ((size_t)n * HW + p0) * C + c0;
  const int pc = t >> 6;
  const int cc = t & 63;
#pragma unroll
  for (int i = 0; i < 16; ++i)
    dst[(size_t)(pc + i * 4) * C + cc] = (bf16_t)tile[cc][pc + i * 4];
}

// ---------------- all weight transforms in one kernel ------------------------
struct WSrc {
  const float *lw0, *lw1, *lw2;
  const float* w9[9];   // fw0,fw1,fw2,cw0,cw1,cw2,rw0,rw1,rw2
  int O9[9];            // 256,256,256,256,256,240,256,256,12
};
__global__ __launch_bounds__(256)
void weight_prep(WSrc s, bf16_t* __restrict__ LWT0, bf16_t* __restrict__ LWT1,
                 bf16_t* __restrict__ LWT2, bf16_t* __restrict__ W33) {
  int idx = blockIdx.x * 256 + threadIdx.x;
  if (idx < 131072) { LWT0[idx] = (bf16_t)s.lw0[idx]; return; }
  if (idx < 393216) { int i = idx - 131072; LWT1[i] = (bf16_t)s.lw1[i]; return; }
  if (idx < 917504) { int i = idx - 393216; LWT2[i] = (bf16_t)s.lw2[i]; return; }
  int t2 = idx - 917504;
  if (t2 >= 9 * 589824) return;
  int sgi = t2 / 589824;
  int r = t2 - sgi * 589824;
  int kid = r >> 16;            // 9 taps * 65536
  int rem = r & 65535;
  int o = rem >> 8, ci = rem & 255;
  const float* src = s.w9[sgi];
  int O = s.O9[sgi];
  W33[t2] = (o < O) ? (bf16_t)src[((size_t)o * 256 + ci) * 9 + kid] : (bf16_t)0.0f;
}

// ---------------- dst(padded NHWC) += up2(src(padded NHWC)), C == 256 --------
__global__ __launch_bounds__(256)
void up2_add_p(bf16_t* __restrict__ dst, const bf16_t* __restrict__ src,
               int lw, int lhw, int dWp, int dNs, int sWp, int sNs, int tot8) {
  int idx = blockIdx.x * 256 + threadIdx.x;
  if (idx >= tot8) return;
  const int c8 = idx & 31;
  const int pos = idx >> 5;
  const int n = pos >> lhw;
  const int rem = pos & ((1 << lhw) - 1);
  const int y = rem >> lw, x = rem & ((1 << lw) - 1);
  bf16_t* d = dst + ((size_t)n * dNs + (y + 1) * dWp + (x + 1)) * 256 + c8 * 8;
  const bf16_t* sp = src + ((size_t)n * sNs + ((y >> 1) + 1) * sWp + ((x >> 1) + 1)) * 256 + c8 * 8;
  bf16x8 dv = *(bf16x8*)d;
  bf16x8 sv = *(const bf16x8*)sp;
#pragma unroll
  for (int k = 0; k < 8; ++k) dv[k] = (bf16_t)((float)dv[k] + (float)sv[k]);
  *(bf16x8*)d = dv;
}

// ---------------- 1x1 conv (laterals), bf16 MFMA, global_load_lds ------------
struct Job1 {
  const bf16_t* A;    // unpadded NHWC
  const bf16_t* Wt;   // [256][Cin]
  const float* bias;
  bf16_t* outb;       // padded NHWC out
  int mtiles, lw, lhw, oWp, onstride, Cin, pad0, pad1;
};
struct Job1Pack { Job1 j[3]; };

__global__ __launch_bounds__(256, 2)
void conv1_batch(Job1Pack jp) {
  __shared__ __align__(16) bf16_t As[128 * 32];
  __shared__ __align__(16) bf16_t Bs[128 * 32];
  int b = blockIdx.x, ji = 0;
#pragma unroll 1
  for (; ji < 2; ++ji) {
    int sz = jp.j[ji].mtiles * 2;
    if (b < sz) break;
    b -= sz;
  }
  const Job1 J = jp.j[ji];
  const int nt = b & 1, mt = b >> 1;
  const int m0 = mt * 128, n0 = nt * 128;
  const int t = threadIdx.x, l = t & 63, w = t >> 6;
  const int W = 1 << J.lw, HW = 1 << J.lhw;
  const int sr = l >> 2, seg = (l & 3) * 8;
  const bf16_t* aptr[2];
  const bf16_t* bptr[2];
  bf16_t* alds[2];
  bf16_t* blds[2];
#pragma unroll
  for (int q = 0; q < 2; ++q) {
    const int r = w * 32 + q * 16 + sr;
    aptr[q] = J.A + (size_t)(m0 + r) * J.Cin + seg;
    alds[q] = &As[(w * 32 + q * 16) * 32];
    bptr[q] = J.Wt + (size_t)(n0 + r) * J.Cin + seg;
    blds[q] = &Bs[(w * 32 + q * 16) * 32];
  }
  const int fr = l & 15, qd = l >> 4;
  const int wm = (w & 1) * 64, wn = (w >> 1) * 64;

  f32x4 acc[4][4];
#pragma unroll
  for (int i = 0; i < 4; ++i)
#pragma unroll
    for (int j = 0; j < 4; ++j)
#pragma unroll
      for (int r = 0; r < 4; ++r) acc[i][j][r] = 0.0f;

  const int kiters = J.Cin >> 5;
#pragma unroll 1
  for (int kk = 0; kk < kiters; ++kk) {
    __syncthreads();
    gl_lds16(aptr[0], alds[0]);
    gl_lds16(aptr[1], alds[1]);
    gl_lds16(bptr[0], blds[0]);
    gl_lds16(bptr[1], blds[1]);
    __syncthreads();
    aptr[0] += 32; aptr[1] += 32; bptr[0] += 32; bptr[1] += 32;
    bf16x8 af[4], bfv[4];
#pragma unroll
    for (int i = 0; i < 4; ++i)
      af[i] = *(const bf16x8*)&As[(wm + i * 16 + fr) * 32 + qd * 8];
#pragma unroll
    for (int j = 0; j < 4; ++j)
      bfv[j] = *(const bf16x8*)&Bs[(wn + j * 16 + fr) * 32 + qd * 8];
#pragma unroll
    for (int i = 0; i < 4; ++i)
#pragma unroll
      for (int j = 0; j < 4; ++j)
        acc[i][j] = __builtin_amdgcn_mfma_f32_16x16x32_bf16(af[i], bfv[j],
                                                            acc[i][j], 0, 0, 0);
  }

#pragma unroll
  for (int i = 0; i < 4; ++i) {
    const int mrow = m0 + wm + i * 16 + qd * 4;
#pragma unroll
    for (int j = 0; j < 4; ++j) {
      const int co = n0 + wn + j * 16 + fr;
      const float bv = J.bias[co];
#pragma unroll
      for (int r = 0; r < 4; ++r) {
        float v = acc[i][j][r] + bv;
        const int m = mrow + r;
        const int n = m >> J.lhw, hw = m & (HW - 1);
        const int y = hw >> J.lw, x = hw & (W - 1);
        J.outb[((size_t)n * J.onstride + (y + 1) * J.oWp + (x + 1)) * 256 + co] =
            (bf16_t)v;
      }
    }
  }
}

// ---------------- 3x3 conv with spatial A-reuse in LDS, Cin==256 -------------
struct Job3 {
  const bf16_t* A;    // padded NHWC (halo zeros), pitch Wp, per-image nsA pixels
  const bf16_t* Wt;   // [9][256][256]
  const float* bias;
  bf16_t* outb;       // padded NHWC out (or null -> outf)
  int mtiles, ntiles, lw, lhw, Wp, nsA, oWp, onstride;
  int relu, Cout, pos_off, ch_off, use_outf, nAr, Pc, pad_;
};
struct Job3Pack { Job3 j[6]; };

__global__ __launch_bounds__(256, 3)
void conv3_batch(Job3Pack jp, float* __restrict__ outf) {
  __shared__ __align__(16) bf16_t As[320 * 32];   // spatial tile, 32 ch slice
  __shared__ __align__(16) bf16_t Bs[384 * 32];   // 3 taps x 128 co x 32 ci
  int b = blockIdx.x, ji = 0;
#pragma unroll 1
  for (; ji < 5; ++ji) {
    int sz = jp.j[ji].mtiles * jp.j[ji].ntiles;
    if (b < sz) break;
    b -= sz;
  }
  const Job3 J = jp.j[ji];
  const int nt = (J.ntiles == 2) ? (b & 1) : 0;
  const int mt = (J.ntiles == 2) ? (b >> 1) : b;
  const int m0 = mt * 128, n0 = nt * 128;
  const int t = threadIdx.x, l = t & 63, w = t >> 6;
  const int W = 1 << J.lw, HW = 1 << J.lhw;
  const int sr = l >> 2, seg = (l & 3) * 8;
  const int fr = l & 15, qd = l >> 4;
  const int wm = (w & 1) * 64, wn = (w >> 1) * 64;

  const int n_img = m0 >> J.lhw;
  const int Y0 = (m0 & (HW - 1)) >> J.lw;
  const bf16_t* Ag = J.A + ((size_t)n_img * J.nsA + (size_t)Y0 * J.Wp) * 256;

  // per-lane A-fragment base pixel offsets (tap (0,0) would be +(Wp+1)*32)
  int apix[4];
#pragma unroll
  for (int i = 0; i < 4; ++i) {
    const int m = wm + i * 16 + fr;
    const int y = m >> J.lw, x = m & (W - 1);
    apix[i] = ((y + 1) * J.Wp + (x + 1)) * 32 + qd * 8;
  }

  f32x4 acc[4][4];
#pragma unroll
  for (int i = 0; i < 4; ++i)
#pragma unroll
    for (int j = 0; j < 4; ++j)
#pragma unroll
      for (int r = 0; r < 4; ++r) acc[i][j][r] = 0.0f;

#pragma unroll 1
  for (int cb = 0; cb < 8; ++cb) {
    const int cboff = cb * 32;
#pragma unroll 1
    for (int ky = 0; ky < 3; ++ky) {
      __syncthreads();
      // stage B: taps (ky,0..2) -> 384 rows of 32ch, 6 rounds
#pragma unroll
      for (int r = 0; r < 6; ++r) {
        const int R = r * 64 + w * 16 + sr;
        const int tp = R >> 7, co = R & 127;
        gl_lds16(J.Wt + (size_t)(ky * 3 + tp) * 65536 +
                     (size_t)(n0 + co) * 256 + cboff + seg,
                 &Bs[(r * 64 + w * 16) * 32]);
      }
      if (ky == 0) {
        // stage A: Pc contiguous padded pixels, 32-ch slice
#pragma unroll 1
        for (int r = 0; r < J.nAr; ++r) {
          int p = r * 64 + w * 16 + sr;
          p = (p < J.Pc) ? p : (J.Pc - 1);
          gl_lds16(Ag + (size_t)p * 256 + cboff + seg,
                   &As[(r * 64 + w * 16) * 32]);
        }
      }
      __syncthreads();
      const int dyoff = (ky - 1) * J.Wp * 32;
#pragma unroll
      for (int kx = 0; kx < 3; ++kx) {
        const int d = dyoff + (kx - 1) * 32;
        bf16x8 af[4], bfv[4];
#pragma unroll
        for (int i = 0; i < 4; ++i)
          af[i] = *(const bf16x8*)&As[apix[i] + d];
#pragma unroll
        for (int j = 0; j < 4; ++j)
          bfv[j] = *(const bf16x8*)&Bs[(kx * 128 + wn + j * 16 + fr) * 32 + qd * 8];
#pragma unroll
        for (int i = 0; i < 4; ++i)
#pragma unroll
          for (int j = 0; j < 4; ++j)
            acc[i][j] = __builtin_amdgcn_mfma_f32_16x16x32_bf16(af[i], bfv[j],
                                                                acc[i][j], 0, 0, 0);
      }
    }
  }

  // epilogue: D layout col=lane&15, row=(lane>>4)*4+reg
#pragma unroll
  for (int i = 0; i < 4; ++i) {
    const int mrow = m0 + wm + i * 16 + qd * 4;
#pragma unroll
    for (int j = 0; j < 4; ++j) {
      const int co = n0 + wn + j * 16 + fr;
      if (co < J.Cout) {
        const float bv = J.bias[co];
#pragma unroll
        for (int r = 0; r < 4; ++r) {
          float v = acc[i][j][r] + bv;
          if (J.relu) v = fmaxf(v, 0.0f);
          const int m = mrow + r;
          const int n = m >> J.lhw, hw = m & (HW - 1);
          if (J.use_outf) {
            outf[((size_t)n * 5376 + J.pos_off + hw) * 252 + J.ch_off + co] = v;
          } else {
            const int y = hw >> J.lw, x = hw & (W - 1);
            J.outb[((size_t)n * J.onstride + (y + 1) * J.oWp + (x + 1)) * 256 + co] =
                (bf16_t)v;
          }
        }
      }
    }
  }
}

// ---------------- anchors ----------------------------------------------------
__global__ __launch_bounds__(256)
void anchors_k(float* __restrict__ out) {
  int r = blockIdx.x * 256 + threadIdx.x;
  if (r >= 16128) return;
  int local, w, stride;
  float bs;
  if (r < 12288)      { local = r;          w = 64; stride = 8;  bs = 32.f;  }
  else if (r < 15360) { local = r - 12288;  w = 32; stride = 16; bs = 64.f;  }
  else                { local = r - 15360;  w = 16; stride = 32; bs = 128.f; }
  const int a = local % 3;
  const int s = local / 3;
  const int y = s / w, x = s - y * w;
  const float ar = (a == 0) ? 0.5f : (a == 1) ? 1.0f : 2.0f;
  const float sq = sqrtf(ar);
  const float hw_ = bs * sq * 0.5f, hh = bs / sq * 0.5f;
  const float cx = (float)x * (float)stride, cy = (float)y * (float)stride;
  out[(size_t)r * 4 + 0] = cx - hw_;
  out[(size_t)r * 4 + 1] = cy - hh;
  out[(size_t)r * 4 + 2] = cx + hw_;
  out[(size_t)r * 4 + 3] = cy + hh;
}

// ---------------- launch -----------------------------------------------------
extern "C" void kernel_launch(void* const* d_in, const int* in_sizes, int n_in,
                              void* d_out, int out_size, void* d_ws, size_t ws_size,
                              hipStream_t stream) {
  const float* feat3 = (const float*)d_in[0];
  const float* feat4 = (const float*)d_in[1];
  const float* feat5 = (const float*)d_in[2];
  const float* lw0 = (const float*)d_in[3];  const float* lb0 = (const float*)d_in[4];
  const float* lw1 = (const float*)d_in[5];  const float* lb1 = (const float*)d_in[6];
  const float* lw2 = (const float*)d_in[7];  const float* lb2 = (const float*)d_in[8];
  const float* fw0 = (const float*)d_in[9];  const float* fb0 = (const float*)d_in[10];
  const float* fw1 = (const float*)d_in[11]; const float* fb1 = (const float*)d_in[12];
  const float* fw2 = (const float*)d_in[13]; const float* fb2 = (const float*)d_in[14];
  const float* cw0 = (const float*)d_in[15]; const float* cb0 = (const float*)d_in[16];
  const float* cw1 = (const float*)d_in[17]; const float* cb1 = (const float*)d_in[18];
  const float* cw2 = (const float*)d_in[19]; const float* cb2 = (const float*)d_in[20];
  const float* rw0 = (const float*)d_in[21]; const float* rb0 = (const float*)d_in[22];
  const float* rw1 = (const float*)d_in[23]; const float* rb1 = (const float*)d_in[24];
  const float* rw2 = (const float*)d_in[25]; const float* rb2 = (const float*)d_in[26];

  char* ws = (char*)d_ws;
  float* out = (float*)d_out;

  // ---- workspace layout (bytes) ----
  bf16_t* XS3 = (bf16_t*)(ws + 0);            // 33,554,432
  bf16_t* XS4 = (bf16_t*)(ws + 33554432);     // 16,777,216
  bf16_t* XS5 = (bf16_t*)(ws + 50331648);     //  8,388,608
  bf16_t* Lp0 = (bf16_t*)(ws + 58720256);     // 8*66*66*256*2 = 17,842,176
  bf16_t* Lp1 = (bf16_t*)(ws + 76562432);     // 8*34*34*256*2 =  4,734,976
  bf16_t* Lp2 = (bf16_t*)(ws + 81297408);     // 8*18*18*256*2 =  1,327,104
  bf16_t* Pp0 = (bf16_t*)(ws + 82624512);     // 17,842,176
  bf16_t* Pp1 = (bf16_t*)(ws + 100466688);    //  4,734,976
  bf16_t* Pp2 = (bf16_t*)(ws + 105201664);    //  1,327,104
  bf16_t* LWT0 = (bf16_t*)(ws + 106528768);   //    262,144
  bf16_t* LWT1 = (bf16_t*)(ws + 106790912);   //    524,288
  bf16_t* LWT2 = (bf16_t*)(ws + 107315200);   //  1,048,576
  bf16_t* W33  = (bf16_t*)(ws + 108363776);   // 9 * 1,179,648
  bf16_t* FWT0 = W33 + 0 * 589824;
  bf16_t* FWT1 = W33 + 1 * 589824;
  bf16_t* FWT2 = W33 + 2 * 589824;
  bf16_t* CWT0 = W33 + 3 * 589824;
  bf16_t* CWT1 = W33 + 4 * 589824;
  bf16_t* CWT2 = W33 + 5 * 589824;
  bf16_t* RWT0 = W33 + 6 * 589824;
  bf16_t* RWT1 = W33 + 7 * 589824;
  bf16_t* RWT2 = W33 + 8 * 589824;
  // T region: aliases XS3+XS4 (dead after laterals)
  bf16_t* TAc0 = (bf16_t*)(ws + 0);
  bf16_t* TAr0 = (bf16_t*)(ws + 17842176);
  bf16_t* TAc1 = (bf16_t*)(ws + 35684352);
  bf16_t* TAr1 = (bf16_t*)(ws + 40419328);
  bf16_t* TAc2 = (bf16_t*)(ws + 45154304);
  bf16_t* TAr2 = (bf16_t*)(ws + 46481408);    // end 47,808,512
  bf16_t* TBc0 = Pp0; bf16_t* TBr0 = Lp0;
  bf16_t* TBc1 = Pp1; bf16_t* TBr1 = Lp1;
  bf16_t* TBc2 = Pp2; bf16_t* TBr2 = Lp2;

  // 1. weight prep
  WSrc wsrc;
  wsrc.lw0 = lw0; wsrc.lw1 = lw1; wsrc.lw2 = lw2;
  const float* w9s[9] = {fw0, fw1, fw2, cw0, cw1, cw2, rw0, rw1, rw2};
  int o9s[9] = {256, 256, 256, 256, 256, 240, 256, 256, 12};
  for (int i = 0; i < 9; ++i) { wsrc.w9[i] = w9s[i]; wsrc.O9[i] = o9s[i]; }
  weight_prep<<<dim3(24320), 256, 0, stream>>>(wsrc, LWT0, LWT1, LWT2, W33);

  // 2. activation casts to NHWC bf16
  nchw_to_nhwc<<<dim3(64, 8, 8),  256, 0, stream>>>(feat3, XS3, 512, 4096);
  nchw_to_nhwc<<<dim3(16, 16, 8), 256, 0, stream>>>(feat4, XS4, 1024, 1024);
  nchw_to_nhwc<<<dim3(4, 32, 8),  256, 0, stream>>>(feat5, XS5, 2048, 256);

  // 3. zero padded Lp/Pp region
  hipMemsetAsync(ws + 58720256, 0, 47808512, stream);

  // 4. lateral 1x1 convs
  {
    Job1Pack jp;
    jp.j[0] = {XS3, LWT0, lb0, Lp0, 256, 6, 12, 66, 4356, 512, 0, 0};
    jp.j[1] = {XS4, LWT1, lb1, Lp1, 64, 5, 10, 34, 1156, 1024, 0, 0};
    jp.j[2] = {XS5, LWT2, lb2, Lp2, 16, 4, 8, 18, 324, 2048, 0, 0};
    conv1_batch<<<dim3(672), 256, 0, stream>>>(jp);
  }

  // 5. zero T region (XS3/XS4 now dead)
  hipMemsetAsync(ws + 0, 0, 47808512, stream);

  // 6. top-down fusion
  up2_add_p<<<dim3(1024), 256, 0, stream>>>(Lp1, Lp2, 5, 10, 34, 1156, 18, 324, 262144);
  up2_add_p<<<dim3(4096), 256, 0, stream>>>(Lp0, Lp1, 6, 12, 66, 4356, 34, 1156, 1048576);

  auto mk3 = [](const bf16_t* A, const bf16_t* Wt, const float* bias,
                bf16_t* outb, int mtiles, int ntiles, int lw, int lhw,
                int Wp, int nsA, int oWp, int onstride, int relu, int Cout,
                int pos_off, int ch_off, int use_outf, int nAr, int Pc) {
    Job3 j;
    j.A = A; j.Wt = Wt; j.bias = bias; j.outb = outb;
    j.mtiles = mtiles; j.ntiles = ntiles; j.lw = lw; j.lhw = lhw;
    j.Wp = Wp; j.nsA = nsA; j.oWp = oWp; j.onstride = onstride;
    j.relu = relu; j.Cout = Cout; j.pos_off = pos_off; j.ch_off = ch_off;
    j.use_outf = use_outf; j.nAr = nAr; j.Pc = Pc; j.pad_ = 0;
    return j;
  };
  // level geometry: L0 (lw6,lhw12,Wp66,ns4356,mt256,nAr5,Pc264)
  //                 L1 (lw5,lhw10,Wp34,ns1156,mt64, nAr4,Pc204)
  //                 L2 (lw4,lhw8, Wp18,ns324, mt16, nAr3,Pc180)

  // 7. FPN 3x3 convs (672 blocks)
  {
    Job3Pack jp;
    jp.j[0] = mk3(Lp0, FWT0, fb0, Pp0, 256, 2, 6, 12, 66, 4356, 66, 4356, 0, 256, 0, 0, 0, 5, 264);
    jp.j[1] = mk3(Lp1, FWT1, fb1, Pp1, 64, 2, 5, 10, 34, 1156, 34, 1156, 0, 256, 0, 0, 0, 4, 204);
    jp.j[2] = mk3(Lp2, FWT2, fb2, Pp2, 16, 2, 4, 8, 18, 324, 18, 324, 0, 256, 0, 0, 0, 3, 180);
    jp.j[3] = jp.j[4] = jp.j[5] = jp.j[2];
    jp.j[3].mtiles = jp.j[4].mtiles = jp.j[5].mtiles = 0;
    conv3_batch<<<dim3(672), 256, 0, stream>>>(jp, out);
  }

  // 8. tower stage 1 (1344 blocks)
  {
    Job3Pack jp;
    jp.j[0] = mk3(Pp0, CWT0, cb0, TAc0, 256, 2, 6, 12, 66, 4356, 66, 4356, 1, 256, 0, 0, 0, 5, 264);
    jp.j[1] = mk3(Pp0, RWT0, rb0, TAr0, 256, 2, 6, 12, 66, 4356, 66, 4356, 1, 256, 0, 0, 0, 5, 264);
    jp.j[2] = mk3(Pp1, CWT0, cb0, TAc1, 64, 2, 5, 10, 34, 1156, 34, 1156, 1, 256, 0, 0, 0, 4, 204);
    jp.j[3] = mk3(Pp1, RWT0, rb0, TAr1, 64, 2, 5, 10, 34, 1156, 34, 1156, 1, 256, 0, 0, 0, 4, 204);
    jp.j[4] = mk3(Pp2, CWT0, cb0, TAc2, 16, 2, 4, 8, 18, 324, 18, 324, 1, 256, 0, 0, 0, 3, 180);
    jp.j[5] = mk3(Pp2, RWT0, rb0, TAr2, 16, 2, 4, 8, 18, 324, 18, 324, 1, 256, 0, 0, 0, 3, 180);
    conv3_batch<<<dim3(1344), 256, 0, stream>>>(jp, out);
  }

  // 9. tower stage 2 (1344 blocks)
  {
    Job3Pack jp;
    jp.j[0] = mk3(TAc0, CWT1, cb1, TBc0, 256, 2, 6, 12, 66, 4356, 66, 4356, 1, 256, 0, 0, 0, 5, 264);
    jp.j[1] = mk3(TAr0, RWT1, rb1, TBr0, 256, 2, 6, 12, 66, 4356, 66, 4356, 1, 256, 0, 0, 0, 5, 264);
    jp.j[2] = mk3(TAc1, CWT1, cb1, TBc1, 64, 2, 5, 10, 34, 1156, 34, 1156, 1, 256, 0, 0, 0, 4, 204);
    jp.j[3] = mk3(TAr1, RWT1, rb1, TBr1, 64, 2, 5, 10, 34, 1156, 34, 1156, 1, 256, 0, 0, 0, 4, 204);
    jp.j[4] = mk3(TAc2, CWT1, cb1, TBc2, 16, 2, 4, 8, 18, 324, 18, 324, 1, 256, 0, 0, 0, 3, 180);
    jp.j[5] = mk3(TAr2, RWT1, rb1, TBr2, 16, 2, 4, 8, 18, 324, 18, 324, 1, 256, 0, 0, 0, 3, 180);
    conv3_batch<<<dim3(1344), 256, 0, stream>>>(jp, out);
  }

  // 10. tower stage 3 -> detector output (1008 blocks)
  {
    Job3Pack jp;
    jp.j[0] = mk3(TBc0, CWT2, cb2, nullptr, 256, 2, 6, 12, 66, 4356, 0, 0, 0, 240, 0, 0, 1, 5, 264);
    jp.j[1] = mk3(TBr0, RWT2, rb2, nullptr, 256, 1, 6, 12, 66, 4356, 0, 0, 0, 12, 0, 240, 1, 5, 264);
    jp.j[2] = mk3(TBc1, CWT2, cb2, nullptr, 64, 2, 5, 10, 34, 1156, 0, 0, 0, 240, 4096, 0, 1, 4, 204);
    jp.j[3] = mk3(TBr1, RWT2, rb2, nullptr, 64, 1, 5, 10, 34, 1156, 0, 0, 0, 12, 4096, 240, 1, 4, 204);
    jp.j[4] = mk3(TBc2, CWT2, cb2, nullptr, 16, 2, 4, 8, 18, 324, 0, 0, 0, 240, 5120, 0, 1, 3, 180);
    jp.j[5] = mk3(TBr2, RWT2, rb2, nullptr, 16, 1, 4, 8, 18, 324, 0, 0, 0, 12, 5120, 240, 1, 3, 180);
    conv3_batch<<<dim3(1008), 256, 0, stream>>>(jp, out);
  }

  // 11. anchors
  anchors_k<<<dim3(63), 256, 0, stream>>>(out + 10838016);
}